// Round 8
// baseline (134.676 us; speedup 1.0000x reference)
//
#include <hip/hip_runtime.h>

#define B_   128
#define L_   26
#define C1_  128
#define C2_  64
#define K1_  7
#define K2_  5
#define NPOS 25
#define FEAT (L_*C2_)            // 1664
#define NPAIR (NPOS*(NPOS+1)/2)  // 325

// h1s: [row][c1], row = pos+2 (rows 0,1,28,29 zero pads), stride 132
// w2s: [c2i][k][c1], per-c2i stride 644 (2-way bank alias only = free)
// w1s: [nt][k][c1] transposed -> stage-1 reads lane-consecutive (conflict-free)
#define HROW 132
#define WROW 644

// ---------------------------------------------------------------------------
// Kernel A: conv1 -> conv2 -> featT[b][u]
// grid = 128 b * 4 c2-tiles(16 c2); block = 256
// ---------------------------------------------------------------------------
__global__ __launch_bounds__(256) void conv_kernel(
    const int*   __restrict__ x,
    const float* __restrict__ w1, const float* __restrict__ b1,
    const float* __restrict__ w2, const float* __restrict__ b2,
    float* __restrict__ featT)
{
    __shared__ float h1s[30*HROW];          // 15840B
    __shared__ float w2s[16*WROW];          // 41216B
    __shared__ float w1s[4*K1_*C1_];        // [nt][k][c1], 14336B
    __shared__ int   xs[L_];

    const int bid = blockIdx.x;
    const int b   = bid >> 2;
    const int c2t = bid & 3;
    const int t   = threadIdx.x;

    if (t < L_) xs[t] = x[b*L_ + t];
    if (t < HROW) { h1s[0*HROW+t] = 0.f; h1s[1*HROW+t] = 0.f;
                    h1s[28*HROW+t] = 0.f; h1s[29*HROW+t] = 0.f; }

    // stage w1 TRANSPOSED: global [c1][nt][k] -> lds [nt][k][c1]
    for (int i = t; i < C1_*4*K1_; i += 256) {
        const int c1  = i / (4*K1_);
        const int rem = i - c1*(4*K1_);
        const int nt  = rem / K1_;
        const int k   = rem - nt*K1_;
        w1s[(nt*K1_ + k)*C1_ + c1] = w1[i];
    }

    // stage w2 slice transposed: global [c2][c1][k] -> w2s[c2i][k][c1]
    {
        const float* src = w2 + c2t*16*C1_*K2_;
        for (int idx = t; idx < 16*C1_*K2_; idx += 256) {
            const int c2i = idx / (C1_*K2_);
            const int rem = idx - c2i*(C1_*K2_);
            const int c1  = rem / K2_;
            const int k   = rem - c1*K2_;
            w2s[c2i*WROW + k*C1_ + c1] = src[idx];
        }
    }
    __syncthreads();

    // stage 1: h1s[l+2][c1] = relu(b1 + sum_k w1[c1][x[l+k-3]][k])
    // w1s read: lanes c1-consecutive -> conflict-free; xs broadcast.
    for (int idx = t; idx < C1_*L_; idx += 256) {
        const int c1 = idx & 127;
        const int l  = idx >> 7;
        float s = b1[c1];
        #pragma unroll
        for (int k = 0; k < K1_; ++k) {
            const int pos = l + k - 3;
            if (pos >= 0 && pos < L_)
                s += w1s[(xs[pos]*K1_ + k)*C1_ + c1];
        }
        h1s[(l+2)*HROW + c1] = fmaxf(s, 0.f);
    }
    __syncthreads();

    // stage 2: thread (c2i = t&15, lg = t>>4 in 0..12) -> l0=2lg, l1=2lg+1
    if (t < 16*13) {
        const int c2i = t & 15;
        const int lg  = t >> 4;
        const int l0  = 2*lg, l1 = 2*lg + 1;
        float a0 = 0.f, a1 = 0.f, a2 = 0.f, a3 = 0.f;
        #pragma unroll
        for (int k = 0; k < K2_; ++k) {
            const float4* wrow = (const float4*)&w2s[c2i*WROW + k*C1_];
            const float4* h0r  = (const float4*)&h1s[(l0 + k)*HROW];
            const float4* h1r  = (const float4*)&h1s[(l1 + k)*HROW];
            #pragma unroll
            for (int cq = 0; cq < 32; cq += 2) {
                const float4 w0 = wrow[cq],  w1v = wrow[cq+1];
                const float4 x0 = h0r[cq],   x1 = h0r[cq+1];
                const float4 y0 = h1r[cq],   y1 = h1r[cq+1];
                a0 += w0.x*x0.x + w0.y*x0.y + w0.z*x0.z + w0.w*x0.w;
                a1 += w1v.x*x1.x + w1v.y*x1.y + w1v.z*x1.z + w1v.w*x1.w;
                a2 += w0.x*y0.x + w0.y*y0.y + w0.z*y0.z + w0.w*y0.w;
                a3 += w1v.x*y1.x + w1v.y*y1.y + w1v.z*y1.z + w1v.w*y1.w;
            }
        }
        const int   c2  = c2t*16 + c2i;
        const float bb  = b2[c2];
        featT[b*FEAT + l0*C2_ + c2] = fmaxf(a0 + a1 + bb, 0.f);
        featT[b*FEAT + l1*C2_ + c2] = fmaxf(a2 + a3 + bb, 0.f);
    }
}

// ---------------------------------------------------------------------------
// Kernel B: pair blocks write PLAIN per-pair partials part[bid][b] (no
// atomics, no memset dependency). Register-bounded inner loop (sp[16]).
// ---------------------------------------------------------------------------
__global__ __launch_bounds__(512) void reg_kernel(
    const float* __restrict__ featT,
    const float* __restrict__ rw, const float* __restrict__ rb,
    float* __restrict__ part)
{
    __shared__ float ws[64*64];   // 16KB
    __shared__ float red[512];
    const int t = threadIdx.x;
    const int b = t & 127;
    const int quarter = t >> 7;
    const int bid = blockIdx.x;

    float acc = 0.f;

    if (bid == NPAIR) {                      // first order + const
        const int u0 = quarter * (FEAT/4);
        const float4* fp = (const float4*)&featT[b*FEAT + u0];
        float a0 = 0.f, a1 = 0.f, a2 = 0.f, a3 = 0.f;
        for (int q = 0; q < FEAT/16; ++q) {  // 104 float4
            const float4 f = fp[q];
            const int u = u0 + q*4;
            a0 += f.x*rw[1+u]; a1 += f.y*rw[2+u];
            a2 += f.z*rw[3+u]; a3 += f.w*rw[4+u];
        }
        acc = (a0+a1)+(a2+a3);
        if (quarter == 0 && b == 0) acc += rw[0] + rb[0];
    } else {
        int i = 0, r = bid;
        while (r >= NPOS - i) { r -= NPOS - i; ++i; }
        const int j = i + 1 + r;

        const int stride = (NPOS - i) * 64;
        const int base   = 1 + FEAT + 4096*(NPOS*i - (i*(i-1))/2)
                         + (j - i - 1)*64;

        // stage W_ij rows into ws (coalesced over q)
        #pragma unroll
        for (int k = 0; k < 8; ++k) {
            const int idx = t + k*512;
            ws[idx] = rw[base + (idx >> 6)*stride + (idx & 63)];
        }
        __syncthreads();

        const int p0 = quarter * 16;
        float sp[16];
        #pragma unroll
        for (int pp = 0; pp < 16; ++pp) sp[pp] = 0.f;

        const float4* fjp = (const float4*)&featT[b*FEAT + j*64];
        #pragma unroll 4
        for (int qq = 0; qq < 16; ++qq) {
            const float4 f = fjp[qq];                 // L2-hit stream
            #pragma unroll
            for (int pp = 0; pp < 16; ++pp) {         // wave-uniform LDS rows
                const float4 w = *(const float4*)&ws[(p0 + pp)*64 + qq*4];
                sp[pp] += w.x*f.x + w.y*f.y + w.z*f.z + w.w*f.w;
            }
        }

        const float4* fip = (const float4*)&featT[b*FEAT + i*64 + p0];
        #pragma unroll
        for (int pq = 0; pq < 4; ++pq) {
            const float4 f = fip[pq];
            acc += f.x*sp[4*pq+0] + f.y*sp[4*pq+1]
                 + f.z*sp[4*pq+2] + f.w*sp[4*pq+3];
        }
    }

    red[t] = acc;
    __syncthreads();
    if (t < B_)
        part[bid*B_ + t] = (red[t] + red[t+128]) + (red[t+256] + red[t+384]);
}

// ---------------------------------------------------------------------------
// finalize: out[b] = sum over 326 partials (coalesced rows, 4-way ILP)
// ---------------------------------------------------------------------------
__global__ __launch_bounds__(128) void fin_kernel(
    const float* __restrict__ part, float* __restrict__ out)
{
    const int b = threadIdx.x;
    float s0 = 0.f, s1 = 0.f, s2 = 0.f, s3 = 0.f;
    int p = 0;
    for (; p + 4 <= NPAIR + 1; p += 4) {
        s0 += part[(p+0)*B_ + b];
        s1 += part[(p+1)*B_ + b];
        s2 += part[(p+2)*B_ + b];
        s3 += part[(p+3)*B_ + b];
    }
    for (; p < NPAIR + 1; ++p) s0 += part[p*B_ + b];
    out[b] = (s0 + s1) + (s2 + s3);
}

// ---------------------------------------------------------------------------
extern "C" void kernel_launch(void* const* d_in, const int* in_sizes, int n_in,
                              void* d_out, int out_size, void* d_ws, size_t ws_size,
                              hipStream_t stream)
{
    const int*   x  = (const int*)  d_in[0];
    const float* w1 = (const float*)d_in[1];
    const float* b1 = (const float*)d_in[2];
    const float* w2 = (const float*)d_in[3];
    const float* b2 = (const float*)d_in[4];
    const float* rw = (const float*)d_in[5];
    const float* rb = (const float*)d_in[6];
    float* out   = (float*)d_out;
    float* featT = (float*)d_ws;                     // 128*1664*4 = 851968 B
    float* part  = (float*)((char*)d_ws + 851968);   // 326*128*4  = 166912 B

    conv_kernel<<<dim3(512), dim3(256), 0, stream>>>(x, w1, b1, w2, b2, featT);
    reg_kernel <<<dim3(NPAIR+1), dim3(512), 0, stream>>>(featT, rw, rb, part);
    fin_kernel <<<dim3(1), dim3(128), 0, stream>>>(part, out);
}

// Round 9
// 115.325 us; speedup vs baseline: 1.1678x; 1.1678x over previous
//
#include <hip/hip_runtime.h>

#define B_   128
#define L_   26
#define C1_  128
#define C2_  64
#define K1_  7
#define K2_  5
#define NPOS 25
#define FEAT (L_*C2_)            // 1664
#define NPAIR (NPOS*(NPOS+1)/2)  // 325

#define HROW 132
#define WROW 644

// ---------------------------------------------------------------------------
// Kernel A: conv1 -> conv2 -> featT[u][b]  (u = l*64+c2; b innermost =
// lane-coalesced for kernel B). Identical to round 8 except the 2 stores.
// ---------------------------------------------------------------------------
__global__ __launch_bounds__(256) void conv_kernel(
    const int*   __restrict__ x,
    const float* __restrict__ w1, const float* __restrict__ b1,
    const float* __restrict__ w2, const float* __restrict__ b2,
    float* __restrict__ featT)
{
    __shared__ float h1s[30*HROW];          // 15840B
    __shared__ float w2s[16*WROW];          // 41216B
    __shared__ float w1s[4*K1_*C1_];        // [nt][k][c1], 14336B
    __shared__ int   xs[L_];

    const int bid = blockIdx.x;
    const int b   = bid >> 2;
    const int c2t = bid & 3;
    const int t   = threadIdx.x;

    if (t < L_) xs[t] = x[b*L_ + t];
    if (t < HROW) { h1s[0*HROW+t] = 0.f; h1s[1*HROW+t] = 0.f;
                    h1s[28*HROW+t] = 0.f; h1s[29*HROW+t] = 0.f; }

    for (int i = t; i < C1_*4*K1_; i += 256) {
        const int c1  = i / (4*K1_);
        const int rem = i - c1*(4*K1_);
        const int nt  = rem / K1_;
        const int k   = rem - nt*K1_;
        w1s[(nt*K1_ + k)*C1_ + c1] = w1[i];
    }

    {
        const float* src = w2 + c2t*16*C1_*K2_;
        for (int idx = t; idx < 16*C1_*K2_; idx += 256) {
            const int c2i = idx / (C1_*K2_);
            const int rem = idx - c2i*(C1_*K2_);
            const int c1  = rem / K2_;
            const int k   = rem - c1*K2_;
            w2s[c2i*WROW + k*C1_ + c1] = src[idx];
        }
    }
    __syncthreads();

    for (int idx = t; idx < C1_*L_; idx += 256) {
        const int c1 = idx & 127;
        const int l  = idx >> 7;
        float s = b1[c1];
        #pragma unroll
        for (int k = 0; k < K1_; ++k) {
            const int pos = l + k - 3;
            if (pos >= 0 && pos < L_)
                s += w1s[(xs[pos]*K1_ + k)*C1_ + c1];
        }
        h1s[(l+2)*HROW + c1] = fmaxf(s, 0.f);
    }
    __syncthreads();

    if (t < 16*13) {
        const int c2i = t & 15;
        const int lg  = t >> 4;
        const int l0  = 2*lg, l1 = 2*lg + 1;
        float a0 = 0.f, a1 = 0.f, a2 = 0.f, a3 = 0.f;
        #pragma unroll
        for (int k = 0; k < K2_; ++k) {
            const float4* wrow = (const float4*)&w2s[c2i*WROW + k*C1_];
            const float4* h0r  = (const float4*)&h1s[(l0 + k)*HROW];
            const float4* h1r  = (const float4*)&h1s[(l1 + k)*HROW];
            #pragma unroll
            for (int cq = 0; cq < 32; cq += 2) {
                const float4 w0 = wrow[cq],  w1v = wrow[cq+1];
                const float4 x0 = h0r[cq],   x1 = h0r[cq+1];
                const float4 y0 = h1r[cq],   y1 = h1r[cq+1];
                a0 += w0.x*x0.x + w0.y*x0.y + w0.z*x0.z + w0.w*x0.w;
                a1 += w1v.x*x1.x + w1v.y*x1.y + w1v.z*x1.z + w1v.w*x1.w;
                a2 += w0.x*y0.x + w0.y*y0.y + w0.z*y0.z + w0.w*y0.w;
                a3 += w1v.x*y1.x + w1v.y*y1.y + w1v.z*y1.z + w1v.w*y1.w;
            }
        }
        const int   c2  = c2t*16 + c2i;
        const float bb  = b2[c2];
        featT[(l0*C2_ + c2)*B_ + b] = fmaxf(a0 + a1 + bb, 0.f);   // [u][b]
        featT[(l1*C2_ + c2)*B_ + b] = fmaxf(a2 + a3 + bb, 0.f);
    }
}

// ---------------------------------------------------------------------------
// Kernel B: block 256 = 4 waves; wave = p-quarter (16 rows), lane = b0=t&63,
// thread covers b0 AND b0+64 (halves W broadcast traffic: 1024 b128/block).
// featT[u][b] -> every featT access is lane-coalesced (256B/instr).
// ws reads wave-uniform b128 broadcast. sp0/sp1 statically indexed (~55 VGPR).
// ---------------------------------------------------------------------------
__global__ __launch_bounds__(256) void reg_kernel(
    const float* __restrict__ featT,
    const float* __restrict__ rw, const float* __restrict__ rb,
    float* __restrict__ part)
{
    __shared__ float ws[64*64];     // 16KB
    __shared__ float red0[256], red1[256];
    const int t  = threadIdx.x;
    const int b0 = t & 63;
    const int wv = t >> 6;          // 0..3
    const int bid = blockIdx.x;

    float acc0 = 0.f, acc1 = 0.f;

    if (bid == NPAIR) {             // first order + const
        const int u0 = wv * (FEAT/4);
        for (int u = u0; u < u0 + FEAT/4; ++u) {
            const float w = rw[1 + u];              // wave-uniform -> s_load
            acc0 += featT[u*B_ + b0]      * w;      // coalesced
            acc1 += featT[u*B_ + b0 + 64] * w;
        }
        if (wv == 0) { const float c = rw[0] + rb[0]; acc0 += c; acc1 += c; }
    } else {
        int i = 0, r = bid;
        while (r >= NPOS - i) { r -= NPOS - i; ++i; }
        const int j = i + 1 + r;

        const int stride = (NPOS - i) * 64;
        const int base   = 1 + FEAT + 4096*(NPOS*i - (i*(i-1))/2)
                         + (j - i - 1)*64;

        // stage W_ij (64 rows x 64 q) coalesced over q
        #pragma unroll
        for (int k = 0; k < 16; ++k) {
            const int idx = t + k*256;
            ws[idx] = rw[base + (idx >> 6)*stride + (idx & 63)];
        }
        __syncthreads();

        const int p0 = wv * 16;
        float sp0[16], sp1[16];
        #pragma unroll
        for (int pp = 0; pp < 16; ++pp) { sp0[pp] = 0.f; sp1[pp] = 0.f; }

        const float* fj = &featT[j*64*B_ + b0];
        #pragma unroll 4
        for (int g = 0; g < 16; ++g) {
            const float f00 = fj[(g*4+0)*B_],      f01 = fj[(g*4+1)*B_],
                        f02 = fj[(g*4+2)*B_],      f03 = fj[(g*4+3)*B_];
            const float f10 = fj[(g*4+0)*B_ + 64], f11 = fj[(g*4+1)*B_ + 64],
                        f12 = fj[(g*4+2)*B_ + 64], f13 = fj[(g*4+3)*B_ + 64];
            #pragma unroll
            for (int pp = 0; pp < 16; ++pp) {
                const float4 w = *(const float4*)&ws[(p0 + pp)*64 + g*4];
                sp0[pp] += w.x*f00 + w.y*f01 + w.z*f02 + w.w*f03;
                sp1[pp] += w.x*f10 + w.y*f11 + w.z*f12 + w.w*f13;
            }
        }

        const float* fi = &featT[(i*64 + p0)*B_ + b0];
        #pragma unroll
        for (int pp = 0; pp < 16; ++pp) {
            acc0 += fi[pp*B_]      * sp0[pp];
            acc1 += fi[pp*B_ + 64] * sp1[pp];
        }
    }

    red0[t] = acc0;
    red1[t] = acc1;
    __syncthreads();
    if (t < B_) {
        const int bb = t & 63;
        const float* rr = (t < 64) ? red0 : red1;
        part[bid*B_ + t] = (rr[bb] + rr[64+bb]) + (rr[128+bb] + rr[192+bb]);
    }
}

// ---------------------------------------------------------------------------
// finalize: out[b] = sum over 326 partials (coalesced, 4-way ILP)
// ---------------------------------------------------------------------------
__global__ __launch_bounds__(128) void fin_kernel(
    const float* __restrict__ part, float* __restrict__ out)
{
    const int b = threadIdx.x;
    float s0 = 0.f, s1 = 0.f, s2 = 0.f, s3 = 0.f;
    int p = 0;
    for (; p + 4 <= NPAIR + 1; p += 4) {
        s0 += part[(p+0)*B_ + b];
        s1 += part[(p+1)*B_ + b];
        s2 += part[(p+2)*B_ + b];
        s3 += part[(p+3)*B_ + b];
    }
    for (; p < NPAIR + 1; ++p) s0 += part[p*B_ + b];
    out[b] = (s0 + s1) + (s2 + s3);
}

// ---------------------------------------------------------------------------
extern "C" void kernel_launch(void* const* d_in, const int* in_sizes, int n_in,
                              void* d_out, int out_size, void* d_ws, size_t ws_size,
                              hipStream_t stream)
{
    const int*   x  = (const int*)  d_in[0];
    const float* w1 = (const float*)d_in[1];
    const float* b1 = (const float*)d_in[2];
    const float* w2 = (const float*)d_in[3];
    const float* b2 = (const float*)d_in[4];
    const float* rw = (const float*)d_in[5];
    const float* rb = (const float*)d_in[6];
    float* out   = (float*)d_out;
    float* featT = (float*)d_ws;                     // 128*1664*4 = 851968 B
    float* part  = (float*)((char*)d_ws + 851968);   // 326*128*4  = 166912 B

    conv_kernel<<<dim3(512), dim3(256), 0, stream>>>(x, w1, b1, w2, b2, featT);
    reg_kernel <<<dim3(NPAIR+1), dim3(256), 0, stream>>>(featT, rw, rb, part);
    fin_kernel <<<dim3(1), dim3(128), 0, stream>>>(part, out);
}